// Round 1
// baseline (286.477 us; speedup 1.0000x reference)
//
#include <hip/hip_runtime.h>
#include <hip/hip_bf16.h>

#define B_DIM 16
#define KQ    2048
#define W_DIM 2048
#define D_DIM 128
#define QBLK  64
#define KVB   64
#define NITER (W_DIM / KVB)

typedef float f4 __attribute__((ext_vector_type(4)));
typedef float f32x4 __attribute__((ext_vector_type(4)));
typedef __bf16 bf16x8 __attribute__((ext_vector_type(8)));
typedef unsigned short u16x4 __attribute__((ext_vector_type(4)));

static __device__ __forceinline__ unsigned short f2bf(float x) {
  __bf16 h = (__bf16)x;
  return __builtin_bit_cast(unsigned short, h);
}

__global__ __launch_bounds__(256, 2)
void diffattn(const float* __restrict__ Q1g, const float* __restrict__ Q2g,
              const float* __restrict__ K1g, const float* __restrict__ K2g,
              const float* __restrict__ Vg, const float* __restrict__ lamp,
              float* __restrict__ Og)
{
  // K tiles: [KVB][D] bf16, row stride 256B, swizzle byte^=((row&7)<<4) (16B gran)
  __shared__ unsigned short sK1[KVB * D_DIM];
  __shared__ unsigned short sK2[KVB * D_DIM];
  // V transposed: [D][KVB] bf16, row stride 128B, swizzle s(d) at 8B gran
  __shared__ unsigned short sVt[D_DIM * KVB];
  // P buffers: per (wave, stream): [16][KVB] bf16, row stride 128B
  __shared__ unsigned short sP[8][16 * KVB];

  const int tid  = threadIdx.x;
  const int wave = tid >> 6;
  const int lane = tid & 63;
  const int g    = lane >> 4;   // 16-lane group 0..3
  const int r    = lane & 15;

  // XCD-aware bijective swizzle: 512 blocks = 8 XCDs x 64 contiguous
  const int wg  = blockIdx.x;
  const int swz = (wg & 7) * 64 + (wg >> 3);
  const int qt  = swz & 31;
  const int b   = swz >> 5;
  const int q0  = qt * QBLK;

  const float scale = 0.08838834764831845f; // 1/sqrt(128)

  // ---- Q fragments (pre-scaled), A-operand layout: row=r, k = kc*32 + g*8 + i
  bf16x8 qf[2][4];
  {
    const float* q1p = Q1g + ((size_t)b * KQ + q0 + wave * 16 + r) * D_DIM;
    const float* q2p = Q2g + ((size_t)b * KQ + q0 + wave * 16 + r) * D_DIM;
#pragma unroll
    for (int kc = 0; kc < 4; ++kc) {
      const int off = kc * 32 + g * 8;
      f4 lo1 = *(const f4*)(q1p + off);
      f4 hi1 = *(const f4*)(q1p + off + 4);
      f4 lo2 = *(const f4*)(q2p + off);
      f4 hi2 = *(const f4*)(q2p + off + 4);
      bf16x8 t1, t2;
#pragma unroll
      for (int j = 0; j < 4; ++j) {
        t1[j]     = (__bf16)(lo1[j] * scale);
        t1[4 + j] = (__bf16)(hi1[j] * scale);
        t2[j]     = (__bf16)(lo2[j] * scale);
        t2[4 + j] = (__bf16)(hi2[j] * scale);
      }
      qf[0][kc] = t1;
      qf[1][kc] = t2;
    }
  }

  const f32x4 vzero = {0.f, 0.f, 0.f, 0.f};
  f32x4 o[2][8];
#pragma unroll
  for (int st = 0; st < 2; ++st)
#pragma unroll
    for (int dc = 0; dc < 8; ++dc) o[st][dc] = vzero;

  float m_[2][4], l_[2][4];
#pragma unroll
  for (int st = 0; st < 2; ++st)
#pragma unroll
    for (int i = 0; i < 4; ++i) { m_[st][i] = -__builtin_inff(); l_[st][i] = 0.f; }

  const float* k1base = K1g + (size_t)b * W_DIM * D_DIM;
  const float* k2base = K2g + (size_t)b * W_DIM * D_DIM;
  const float* vbase  = Vg  + (size_t)b * W_DIM * D_DIM;

#pragma unroll 1
  for (int t = 0; t < NITER; ++t) {
    const int w0 = t * KVB;
    __syncthreads();

    // ---- stage K1, K2 (row-major, swizzled) ----
    {
      const float* k1p = k1base + (size_t)w0 * D_DIM;
      const float* k2p = k2base + (size_t)w0 * D_DIM;
#pragma unroll
      for (int it = 0; it < 8; ++it) {
        const int f  = it * 256 + tid;
        const int rw = f >> 5;    // row 0..63
        const int c4 = f & 31;    // float4 col
        const f4 x1 = *(const f4*)(k1p + rw * D_DIM + c4 * 4);
        const f4 x2 = *(const f4*)(k2p + rw * D_DIM + c4 * 4);
        const int boff = rw * 256 + ((c4 * 8) ^ ((rw & 7) << 4));
        u16x4 u1 = { f2bf(x1[0]), f2bf(x1[1]), f2bf(x1[2]), f2bf(x1[3]) };
        u16x4 u2 = { f2bf(x2[0]), f2bf(x2[1]), f2bf(x2[2]), f2bf(x2[3]) };
        *(u16x4*)((char*)sK1 + boff) = u1;
        *(u16x4*)((char*)sK2 + boff) = u2;
      }
      // ---- stage V transposed: Vt[d][w], 4x4 micro-transpose per thread ----
      const float* vp0 = vbase + (size_t)w0 * D_DIM;
#pragma unroll
      for (int it = 0; it < 2; ++it) {
        const int bb = it * 256 + tid;
        const int wq = bb >> 5;   // w-quad 0..15
        const int dq = bb & 31;   // d-quad 0..31
        const float* vp = vp0 + (size_t)(wq * 4) * D_DIM + dq * 4;
        f4 a0 = *(const f4*)(vp);
        f4 a1 = *(const f4*)(vp + D_DIM);
        f4 a2 = *(const f4*)(vp + 2 * D_DIM);
        f4 a3 = *(const f4*)(vp + 3 * D_DIM);
#pragma unroll
        for (int jj = 0; jj < 4; ++jj) {
          const int d  = dq * 4 + jj;
          const int sx = ((d >> 2) + ((d & 3) << 2)) & 15;
          const int boff = d * 128 + ((wq * 8) ^ (sx << 3));
          u16x4 u = { f2bf(a0[jj]), f2bf(a1[jj]), f2bf(a2[jj]), f2bf(a3[jj]) };
          *(u16x4*)((char*)sVt + boff) = u;
        }
      }
    }
    __syncthreads();

    // ---- per-stream: S = QK^T, online softmax, P -> LDS ----
#pragma unroll
    for (int st = 0; st < 2; ++st) {
      const unsigned short* sK = st ? sK2 : sK1;
      f32x4 sa[4];
#pragma unroll
      for (int ct = 0; ct < 4; ++ct) sa[ct] = vzero;
#pragma unroll
      for (int kc = 0; kc < 4; ++kc) {
        const bf16x8 a = qf[st][kc];
#pragma unroll
        for (int ct = 0; ct < 4; ++ct) {
          const int row  = ct * 16 + r;
          const int boff = row * 256 + ((kc * 64 + g * 16) ^ ((row & 7) << 4));
          const bf16x8 kb = *(const bf16x8*)((const char*)sK + boff);
          sa[ct] = __builtin_amdgcn_mfma_f32_16x16x32_bf16(a, kb, sa[ct], 0, 0, 0);
        }
      }
      // lane owns rows 4g+i (i=0..3), cols ct*16+r; reduce across 16-lane group
      float mn[4], corr[4], rs[4];
#pragma unroll
      for (int i = 0; i < 4; ++i) {
        float tm = fmaxf(fmaxf(sa[0][i], sa[1][i]), fmaxf(sa[2][i], sa[3][i]));
        tm = fmaxf(tm, __shfl_xor(tm, 1));
        tm = fmaxf(tm, __shfl_xor(tm, 2));
        tm = fmaxf(tm, __shfl_xor(tm, 4));
        tm = fmaxf(tm, __shfl_xor(tm, 8));
        const float mnew = fmaxf(m_[st][i], tm);
        corr[i] = __expf(m_[st][i] - mnew);
        m_[st][i] = mnew;
        mn[i] = mnew;
        rs[i] = 0.f;
      }
      unsigned short* sPw = &sP[wave * 2 + st][0];
#pragma unroll
      for (int ct = 0; ct < 4; ++ct) {
#pragma unroll
        for (int i = 0; i < 4; ++i) {
          const float p = __expf(sa[ct][i] - mn[i]);
          rs[i] += p;
          const int prow = 4 * g + i;
          const int boff = prow * 128 + ((2 * (ct * 16 + r)) ^ ((prow & 7) << 4));
          *(unsigned short*)((char*)sPw + boff) = f2bf(p);
        }
      }
      f32x4 cv;
#pragma unroll
      for (int i = 0; i < 4; ++i) {
        float s = rs[i];
        s += __shfl_xor(s, 1);
        s += __shfl_xor(s, 2);
        s += __shfl_xor(s, 4);
        s += __shfl_xor(s, 8);
        l_[st][i] = l_[st][i] * corr[i] + s;
        cv[i] = corr[i];
      }
#pragma unroll
      for (int dc = 0; dc < 8; ++dc) o[st][dc] *= cv;
    }

    // ---- PV for both streams, sharing V B-fragments ----
    const unsigned short* sP1 = &sP[wave * 2 + 0][0];
    const unsigned short* sP2 = &sP[wave * 2 + 1][0];
#pragma unroll
    for (int kk = 0; kk < 2; ++kk) {
      const int pboff = r * 128 + ((kk * 64 + g * 16) ^ ((r & 7) << 4));
      const bf16x8 pa1 = *(const bf16x8*)((const char*)sP1 + pboff);
      const bf16x8 pa2 = *(const bf16x8*)((const char*)sP2 + pboff);
#pragma unroll
      for (int dc = 0; dc < 8; ++dc) {
        const int d  = dc * 16 + r;
        const int sx = ((d >> 2) + ((d & 3) << 2)) & 15;
        const int b0 = d * 128 + ((kk * 64 + g * 16) ^ (sx << 3));
        union { u16x4 h[2]; bf16x8 v; } uu;
        uu.h[0] = *(const u16x4*)((const char*)sVt + b0);
        uu.h[1] = *(const u16x4*)((const char*)sVt + (b0 ^ 8));
        o[0][dc] = __builtin_amdgcn_mfma_f32_16x16x32_bf16(pa1, uu.v, o[0][dc], 0, 0, 0);
        o[1][dc] = __builtin_amdgcn_mfma_f32_16x16x32_bf16(pa2, uu.v, o[1][dc], 0, 0, 0);
      }
    }
  }

  // ---- epilogue: out = o1/l1 - lam * o2/l2 ----
  const float lam = 1.f / (1.f + __expf(-lamp[0]));
  float w1[4], w2[4];
#pragma unroll
  for (int i = 0; i < 4; ++i) {
    w1[i] = 1.f / l_[0][i];
    w2[i] = lam / l_[1][i];
  }
  float* op = Og + ((size_t)b * KQ + q0 + wave * 16) * D_DIM;
#pragma unroll
  for (int dc = 0; dc < 8; ++dc) {
#pragma unroll
    for (int i = 0; i < 4; ++i) {
      op[(4 * g + i) * D_DIM + dc * 16 + r] = o[0][dc][i] * w1[i] - o[1][dc][i] * w2[i];
    }
  }
}

extern "C" void kernel_launch(void* const* d_in, const int* in_sizes, int n_in,
                              void* d_out, int out_size, void* d_ws, size_t ws_size,
                              hipStream_t stream) {
  const float* Q1 = (const float*)d_in[0];
  const float* Q2 = (const float*)d_in[1];
  const float* K1 = (const float*)d_in[2];
  const float* K2 = (const float*)d_in[3];
  const float* V  = (const float*)d_in[4];
  const float* lm = (const float*)d_in[5];
  float* O = (float*)d_out;

  dim3 grid(B_DIM * (KQ / QBLK));  // 512 blocks
  dim3 block(256);
  diffattn<<<grid, block, 0, stream>>>(Q1, Q2, K1, K2, V, lm, O);
}

// Round 2
// 134.963 us; speedup vs baseline: 2.1226x; 2.1226x over previous
//
#include <hip/hip_runtime.h>
#include <hip/hip_bf16.h>

#define B_DIM 16
#define KQ    2048
#define W_DIM 2048
#define D_DIM 128
#define QBLK  64
#define KVB   32
#define NT    (W_DIM / KVB)
#define BUFSZ 24576

typedef float f4 __attribute__((ext_vector_type(4)));
typedef float f32x4 __attribute__((ext_vector_type(4)));
typedef __bf16 bf16x8 __attribute__((ext_vector_type(8)));
typedef unsigned short u16x4 __attribute__((ext_vector_type(4)));

static __device__ __forceinline__ unsigned short f2bf(float x) {
  __bf16 h = (__bf16)x;
  return __builtin_bit_cast(unsigned short, h);
}

// LDS buffer layout (per 24KB buffer):
//   [0,     8192)  K1 tile: 32 rows x 128 bf16, row stride 256B, byte ^= ((row&7)<<4)
//   [8192, 16384)  K2 tile: same layout
//   [16384,24576)  Vt tile: 128 d-rows x 32 w (pi-permuted), row stride 64B,
//                  byte ^= (((d>>1)&3)<<4); slot p = ((w>>2)&3)*8 + (w&3) + ((w>>4)&1)*4

__global__ __launch_bounds__(256, 2)
void diffattn(const float* __restrict__ Q1g, const float* __restrict__ Q2g,
              const float* __restrict__ K1g, const float* __restrict__ K2g,
              const float* __restrict__ Vg, const float* __restrict__ lamp,
              float* __restrict__ Og)
{
  __shared__ char smem[2 * BUFSZ];

  const int tid  = threadIdx.x;
  const int wave = tid >> 6;
  const int lane = tid & 63;
  const int g    = lane >> 4;
  const int r    = lane & 15;

  // XCD-aware bijective swizzle: 512 blocks = 8 XCDs x 64
  const int wg  = blockIdx.x;
  const int swz = (wg & 7) * 64 + (wg >> 3);
  const int qt  = swz & 31;
  const int b   = swz >> 5;
  const int q0  = qt * QBLK;

  const float scale = 0.08838834764831845f; // 1/sqrt(128)

  // ---- Q fragments (B-operand; lane holds q-row r, k-slots at d = kc*32+g*8+j)
  bf16x8 qf[2][4];
  {
    const float* q1p = Q1g + ((size_t)b * KQ + q0 + wave * 16 + r) * D_DIM;
    const float* q2p = Q2g + ((size_t)b * KQ + q0 + wave * 16 + r) * D_DIM;
#pragma unroll
    for (int kc = 0; kc < 4; ++kc) {
      const int off = kc * 32 + g * 8;
      f4 lo1 = *(const f4*)(q1p + off);
      f4 hi1 = *(const f4*)(q1p + off + 4);
      f4 lo2 = *(const f4*)(q2p + off);
      f4 hi2 = *(const f4*)(q2p + off + 4);
      bf16x8 t1, t2;
#pragma unroll
      for (int j = 0; j < 4; ++j) {
        t1[j]     = (__bf16)(lo1[j] * scale);
        t1[4 + j] = (__bf16)(hi1[j] * scale);
        t2[j]     = (__bf16)(lo2[j] * scale);
        t2[4 + j] = (__bf16)(hi2[j] * scale);
      }
      qf[0][kc] = t1;
      qf[1][kc] = t2;
    }
  }

  const f32x4 vzero = {0.f, 0.f, 0.f, 0.f};
  f32x4 o[2][8];
#pragma unroll
  for (int st = 0; st < 2; ++st)
#pragma unroll
    for (int dc = 0; dc < 8; ++dc) o[st][dc] = vzero;

  float m_[2] = {-__builtin_inff(), -__builtin_inff()};
  float l_[2] = {0.f, 0.f};

  const float* k1base = K1g + (size_t)b * W_DIM * D_DIM;
  const float* k2base = K2g + (size_t)b * W_DIM * D_DIM;
  const float* vbase  = Vg  + (size_t)b * W_DIM * D_DIM;

  // ---- staging constants (per thread) ----
  const int gk0 = (tid >> 5) * D_DIM + (tid & 31) * 4;                     // K global f32 offset
  const int kb0 = (tid >> 5) * 256 + (((tid & 31) * 8) ^ ((tid >> 5) << 4)); // K LDS byte offset
  const int wq  = tid >> 5;   // 0..7
  const int dq  = tid & 31;   // 0..31
  const int gv0 = wq * 4 * D_DIM + dq * 4;
  int vwoff[4];
#pragma unroll
  for (int jj = 0; jj < 4; ++jj) {
    const int d = dq * 4 + jj;
    vwoff[jj] = 16384 + d * 64 + ((((wq & 3) * 16) + ((wq >> 2) * 8)) ^ (((d >> 1) & 3) << 4));
  }

  // ---- compute constants ----
  int koffx[4];
#pragma unroll
  for (int kc = 0; kc < 4; ++kc) koffx[kc] = (kc * 64 + g * 16) ^ ((r & 7) << 4);
  const int v0 = 16384 + r * 64 + ((g * 16) ^ (((r >> 1) & 3) << 4));

  f4 sk1[4], sk2[4], sv[4];

  auto LOADT = [&](int t) {
    const float* p1 = k1base + (size_t)t * KVB * D_DIM;
    const float* p2 = k2base + (size_t)t * KVB * D_DIM;
    const float* pv = vbase  + (size_t)t * KVB * D_DIM;
#pragma unroll
    for (int it = 0; it < 4; ++it) {
      sk1[it] = *(const f4*)(p1 + it * 1024 + gk0);
      sk2[it] = *(const f4*)(p2 + it * 1024 + gk0);
    }
#pragma unroll
    for (int ii = 0; ii < 4; ++ii)
      sv[ii] = *(const f4*)(pv + gv0 + ii * D_DIM);
  };

  auto WRITET = [&](char* bufp) {
#pragma unroll
    for (int it = 0; it < 4; ++it) {
      u16x4 u1 = { f2bf(sk1[it][0]), f2bf(sk1[it][1]), f2bf(sk1[it][2]), f2bf(sk1[it][3]) };
      u16x4 u2 = { f2bf(sk2[it][0]), f2bf(sk2[it][1]), f2bf(sk2[it][2]), f2bf(sk2[it][3]) };
      *(u16x4*)(bufp + it * 2048 + kb0)        = u1;
      *(u16x4*)(bufp + 8192 + it * 2048 + kb0) = u2;
    }
#pragma unroll
    for (int jj = 0; jj < 4; ++jj) {
      u16x4 u = { f2bf(sv[0][jj]), f2bf(sv[1][jj]), f2bf(sv[2][jj]), f2bf(sv[3][jj]) };
      *(u16x4*)(bufp + vwoff[jj]) = u;
    }
  };

  // prologue: stage tile 0, start loads for tile 1
  LOADT(0);
  WRITET(smem);
  LOADT(1);
  __syncthreads();

#pragma unroll 1
  for (int t = 0; t < NT; ++t) {
    char* bufp = smem + (t & 1) * BUFSZ;
    bf16x8 pa[2];

#pragma unroll
    for (int st = 0; st < 2; ++st) {
      const char* kbase = bufp + st * 8192;
      f32x4 sa[2];
      sa[0] = vzero; sa[1] = vzero;
#pragma unroll
      for (int kc = 0; kc < 4; ++kc) {
        const bf16x8 a0 = *(const bf16x8*)(kbase + r * 256 + koffx[kc]);
        const bf16x8 a1 = *(const bf16x8*)(kbase + r * 256 + 4096 + koffx[kc]);
        sa[0] = __builtin_amdgcn_mfma_f32_16x16x32_bf16(a0, qf[st][kc], sa[0], 0, 0, 0);
        sa[1] = __builtin_amdgcn_mfma_f32_16x16x32_bf16(a1, qf[st][kc], sa[1], 0, 0, 0);
      }
      // lane holds St[w = ct*16 + 4g+i][q = r] — row-reduce across g via 2 shuffles
      float tm = fmaxf(fmaxf(fmaxf(sa[0][0], sa[0][1]), fmaxf(sa[0][2], sa[0][3])),
                       fmaxf(fmaxf(sa[1][0], sa[1][1]), fmaxf(sa[1][2], sa[1][3])));
      tm = fmaxf(tm, __shfl_xor(tm, 16));
      tm = fmaxf(tm, __shfl_xor(tm, 32));
      if (__any(tm > m_[st])) {
        const float mnew = fmaxf(m_[st], tm);
        const float corr = __expf(m_[st] - mnew);
        m_[st] = mnew;
        l_[st] *= corr;
        f32x4 cv;
#pragma unroll
        for (int i = 0; i < 4; ++i) cv[i] = __shfl(corr, 4 * g + i);
#pragma unroll
        for (int dc = 0; dc < 8; ++dc) o[st][dc] *= cv;
      }
      const float m = m_[st];
      float rs = 0.f;
      bf16x8 pv;
#pragma unroll
      for (int ct = 0; ct < 2; ++ct)
#pragma unroll
        for (int i = 0; i < 4; ++i) {
          const float p = __expf(sa[ct][i] - m);
          rs += p;
          pv[ct * 4 + i] = (__bf16)p;   // slot i' = ct*4+i  <->  w = pi(g,i')
        }
      rs += __shfl_xor(rs, 16);
      rs += __shfl_xor(rs, 32);
      l_[st] += rs;
      pa[st] = pv;
    }

    // ---- PV: shared V fragments, P already in registers ----
#pragma unroll
    for (int dc = 0; dc < 8; ++dc) {
      const bf16x8 vb = *(const bf16x8*)(bufp + v0 + dc * 1024);
      o[0][dc] = __builtin_amdgcn_mfma_f32_16x16x32_bf16(pa[0], vb, o[0][dc], 0, 0, 0);
      o[1][dc] = __builtin_amdgcn_mfma_f32_16x16x32_bf16(pa[1], vb, o[1][dc], 0, 0, 0);
    }

    // ---- pipelined staging for t+1 / t+2 ----
    if (t + 1 < NT) {
      WRITET(smem + ((t + 1) & 1) * BUFSZ);
      if (t + 2 < NT) LOADT(t + 2);
    }
    __syncthreads();
  }

  // ---- epilogue: out = o1/l1 - lam * o2/l2 ----
  const float lam = 1.f / (1.f + __expf(-lamp[0]));
  float w1[4], w2[4];
#pragma unroll
  for (int i = 0; i < 4; ++i) {
    const float l1 = __shfl(l_[0], 4 * g + i);
    const float l2 = __shfl(l_[1], 4 * g + i);
    w1[i] = 1.f / l1;
    w2[i] = lam / l2;
  }
  float* op = Og + ((size_t)b * KQ + q0 + wave * 16) * D_DIM;
#pragma unroll
  for (int dc = 0; dc < 8; ++dc) {
#pragma unroll
    for (int i = 0; i < 4; ++i) {
      op[(4 * g + i) * D_DIM + dc * 16 + r] = o[0][dc][i] * w1[i] - o[1][dc][i] * w2[i];
    }
  }
}

extern "C" void kernel_launch(void* const* d_in, const int* in_sizes, int n_in,
                              void* d_out, int out_size, void* d_ws, size_t ws_size,
                              hipStream_t stream) {
  const float* Q1 = (const float*)d_in[0];
  const float* Q2 = (const float*)d_in[1];
  const float* K1 = (const float*)d_in[2];
  const float* K2 = (const float*)d_in[3];
  const float* V  = (const float*)d_in[4];
  const float* lm = (const float*)d_in[5];
  float* O = (float*)d_out;

  dim3 grid(B_DIM * (KQ / QBLK));  // 512 blocks
  dim3 block(256);
  diffattn<<<grid, block, 0, stream>>>(Q1, Q2, K1, K2, V, lm, O);
}